// Round 6
// baseline (121.208 us; speedup 1.0000x reference)
//
#include <hip/hip_runtime.h>
#include <math.h>

#define SH_C0     0.28209479177387814f
#define EPS2D     0.3f
#define NEARZ     0.01f
#define ALPHA_MIN (1.0f/255.0f)
#define ALPHA_MAX 0.999f
#define LOG2E     1.4426950408889634f

#define NSEG 16   // depth segments per tile (= waves per render block)

// ---------------------------------------------------------------------------
// Fused preprocess + stable-rank + scatter. One 64-lane wave per gaussian.
// Record (12 floats, 48B, float4-aligned), indexed by depth rank:
//   r0 = {u, v, rx, ry}            (rx,ry: conservative alpha>=1/255 bbox
//                                   half-extents + 0.5px pad -> culling exact)
//   r1 = {0.5*conA*L2E, conB*L2E, 0.5*conC*L2E, op}
//   r2 = {cr, cg, cb, 0}
// Invalid (z<=NEAR, det<=0) or op<1/255: u=v=-1e9, rx=ry=0 -> culled from
// every tile, which equals the reference's alpha=0 for those gaussians.
// Rank key = (zc > NEAR ? zc : +inf), stable tie-break j<i: permutation
// matches jnp.argsort order exactly for all contributing gaussians.
// ---------------------------------------------------------------------------
__global__ __launch_bounds__(256) void prep_rank_kernel(
        const float* __restrict__ means,
        const float* __restrict__ quats,
        const float* __restrict__ scales,
        const float* __restrict__ opacities,
        const float* __restrict__ sh,
        const float* __restrict__ vm,
        const float* __restrict__ K,
        float* __restrict__ sorted,
        int N) {
    int wave = blockIdx.x * 4 + (threadIdx.x >> 6);
    int lane = threadIdx.x & 63;
    if (wave >= N) return;
    int i = wave;

    float r00=vm[0], r01=vm[1], r02=vm[2],  t0=vm[3];
    float r10=vm[4], r11=vm[5], r12=vm[6],  t1=vm[7];
    float r20=vm[8], r21=vm[9], r22=vm[10], t2=vm[11];

    // --- stable rank: count keys strictly smaller (ties: j < i) ---
    float mx = means[3*i+0], my = means[3*i+1], mz = means[3*i+2];
    float zci = r20*mx + r21*my + r22*mz + t2;
    float keyi = (zci > NEARZ) ? zci : INFINITY;
    int cnt = 0;
    for (int j = lane; j < N; j += 64) {
        float ax = means[3*j+0], ay = means[3*j+1], az = means[3*j+2];
        float zcj = r20*ax + r21*ay + r22*az + t2;
        float keyj = (zcj > NEARZ) ? zcj : INFINITY;
        cnt += (keyj < keyi) || (keyj == keyi && j < i);
    }
    #pragma unroll
    for (int off = 32; off > 0; off >>= 1)
        cnt += __shfl_xor(cnt, off, 64);

    // --- preprocess (redundant across lanes; uniform loads) ---
    float qw = quats[4*i+0], qx = quats[4*i+1], qy = quats[4*i+2], qz = quats[4*i+3];
    float rqn = rsqrtf(qw*qw + qx*qx + qy*qy + qz*qz);
    qw *= rqn; qx *= rqn; qy *= rqn; qz *= rqn;

    float R00 = 1.f - 2.f*(qy*qy + qz*qz);
    float R01 = 2.f*(qx*qy - qw*qz);
    float R02 = 2.f*(qx*qz + qw*qy);
    float R10 = 2.f*(qx*qy + qw*qz);
    float R11 = 1.f - 2.f*(qx*qx + qz*qz);
    float R12 = 2.f*(qy*qz - qw*qx);
    float R20 = 2.f*(qx*qz - qw*qy);
    float R21 = 2.f*(qy*qz + qw*qx);
    float R22 = 1.f - 2.f*(qx*qx + qy*qy);

    float s0 = fminf(expf(scales[3*i+0]), 10.f);
    float s1 = fminf(expf(scales[3*i+1]), 10.f);
    float s2 = fminf(expf(scales[3*i+2]), 10.f);

    float M00=R00*s0, M01=R01*s1, M02=R02*s2;
    float M10=R10*s0, M11=R11*s1, M12=R12*s2;
    float M20=R20*s0, M21=R21*s1, M22=R22*s2;

    float c00 = M00*M00 + M01*M01 + M02*M02;
    float c01 = M00*M10 + M01*M11 + M02*M12;
    float c02 = M00*M20 + M01*M21 + M02*M22;
    float c11 = M10*M10 + M11*M11 + M12*M12;
    float c12 = M10*M20 + M11*M21 + M12*M22;
    float c22 = M20*M20 + M21*M21 + M22*M22;

    float xc = r00*mx + r01*my + r02*mz + t0;
    float yc = r10*mx + r11*my + r12*mz + t1;
    float zc = zci;

    float T00 = r00*c00 + r01*c01 + r02*c02;
    float T01 = r00*c01 + r01*c11 + r02*c12;
    float T02 = r00*c02 + r01*c12 + r02*c22;
    float T10 = r10*c00 + r11*c01 + r12*c02;
    float T11 = r10*c01 + r11*c11 + r12*c12;
    float T12 = r10*c02 + r11*c12 + r12*c22;
    float T20 = r20*c00 + r21*c01 + r22*c02;
    float T21 = r20*c01 + r21*c11 + r22*c12;
    float T22 = r20*c02 + r21*c12 + r22*c22;
    float V00 = T00*r00 + T01*r01 + T02*r02;
    float V01 = T00*r10 + T01*r11 + T02*r12;
    float V02 = T00*r20 + T01*r21 + T02*r22;
    float V11 = T10*r10 + T11*r11 + T12*r12;
    float V12 = T10*r20 + T11*r21 + T12*r22;
    float V22 = T20*r20 + T21*r21 + T22*r22;

    float fx = K[0], cx = K[2], fy = K[4], cy = K[5];

    bool valid = zc > NEARZ;
    float zs = valid ? zc : 1.0f;
    float rz = 1.0f / zs;
    float u = fx*xc*rz + cx;
    float v = fy*yc*rz + cy;
    float J00 = fx*rz;
    float J02 = -fx*xc*rz*rz;
    float J11 = fy*rz;
    float J12 = -fy*yc*rz*rz;

    float a = J00*J00*V00 + 2.f*J00*J02*V02 + J02*J02*V22 + EPS2D;
    float b = J00*(J11*V01 + J12*V02) + J02*(J11*V12 + J12*V22);
    float c = J11*J11*V11 + 2.f*J11*J12*V12 + J12*J12*V22 + EPS2D;
    float det = a*c - b*b;
    valid = valid && (det > 0.f);
    float det_s = valid ? det : 1.0f;
    float conA =  c / det_s;
    float conB = -b / det_s;
    float conC =  a / det_s;

    float op  = 1.0f / (1.0f + expf(-opacities[i]));
    float cr = fmaxf(sh[3*i+0]*SH_C0 + 0.5f, 0.f);
    float cg = fmaxf(sh[3*i+1]*SH_C0 + 0.5f, 0.f);
    float cb = fmaxf(sh[3*i+2]*SH_C0 + 0.5f, 0.f);

    // conservative alpha>=1/255 ellipse half-extents:
    // sigma<=smax region has max|dx| = sqrt(2*smax*conC/(conA*conC-conB^2))
    float smax = logf(op * 255.0f);
    bool vis = valid && (smax > 0.f);
    float denom = conA*conC - conB*conB;
    float rxe = 0.f, rye = 0.f;
    float uu = -1.0e9f, vv = -1.0e9f;
    float e4 = 0.f, e5 = 0.f, e6 = 0.f, e7 = 0.f;
    if (vis) {
        float inv = 2.f * smax / denom;
        rxe = sqrtf(fmaxf(inv * conC, 0.f)) + 0.5f;
        rye = sqrtf(fmaxf(inv * conA, 0.f)) + 0.5f;
        uu = u; vv = v;
        e4 = 0.5f*conA*LOG2E; e5 = conB*LOG2E; e6 = 0.5f*conC*LOG2E; e7 = op;
    }

    if (lane < 12) {
        float val;
        switch (lane) {
            case 0:  val = uu;  break;
            case 1:  val = vv;  break;
            case 2:  val = rxe; break;
            case 3:  val = rye; break;
            case 4:  val = e4;  break;
            case 5:  val = e5;  break;
            case 6:  val = e6;  break;
            case 7:  val = e7;  break;
            case 8:  val = cr;  break;
            case 9:  val = cg;  break;
            case 10: val = cb;  break;
            default: val = 0.f; break;
        }
        sorted[12*(size_t)cnt + lane] = val;
    }
}

// ---------------------------------------------------------------------------
// Tiled render, R4-style uniform scan + wave-uniform early-skip.
// 256 blocks (one per 8x8 tile) x 1024 threads = 16 depth-segment waves.
// Each wave walks a contiguous 128-gaussian segment of the sorted list with
// wave-uniform scalar loads; per gaussian a lane-invariant bbox test
// (readfirstlane -> scalar branch) skips non-overlapping gaussians (~84%).
// Per-wave (C,T) partials folded in depth order via LDS, written to out.
// Conservative culling => output identical to the brute-force version.
// ---------------------------------------------------------------------------
__global__ __launch_bounds__(1024, 4) void render_tile_kernel(
        const float4* __restrict__ rec,
        float* __restrict__ out,
        int N) {
    __shared__ float4 part[NSEG][64];
    int tid  = threadIdx.x;
    int lane = tid & 63;
    int w    = tid >> 6;                 // segment id 0..15
    int t    = blockIdx.x;               // tile id 0..255
    int tx   = (t & 15) << 3;
    int ty   = (t >> 4) << 3;

    float tcx = (float)tx + 4.0f;        // pixel centers span [tx+0.5, tx+7.5]
    float tcy = (float)ty + 4.0f;        // -> center +4.0, half-extent 3.5
    float px  = (float)(tx + (lane & 7)) + 0.5f;
    float py  = (float)(ty + (lane >> 3)) + 0.5f;

    int chunk = (N + NSEG - 1) / NSEG;
    int g0 = w * chunk;
    int g1 = min(g0 + chunk, N);

    const float4* r = rec + 3*(size_t)g0;

    float accr = 0.f, accg = 0.f, accb = 0.f, T = 1.f;
    for (int g = g0; g < g1; ++g, r += 3) {
        float4 r0 = r[0];                            // u, v, rx, ry (s_load)
        float ddx = fabsf(r0.x - tcx) - r0.z;
        float ddy = fabsf(r0.y - tcy) - r0.w;
        bool hit = fmaxf(ddx, ddy) <= 3.5f;          // lane-invariant
        if (__builtin_amdgcn_readfirstlane((int)hit)) {
            float4 r1 = r[1];                        // A2', B', C2', op
            float4 r2 = r[2];                        // cr, cg, cb, -
            float dx = px - r0.x, dy = py - r0.y;
            float tt  = fmaf(r1.x, dx, r1.y * dy);
            float arg = fmaf(-r1.z, dy*dy, -dx*tt);  // -sigma*log2e
            float al  = r1.w * __builtin_amdgcn_exp2f(arg);
            al = fminf(al, ALPHA_MAX);
            al = (al >= ALPHA_MIN) ? al : 0.f;
            float wg = T * al;
            accr = fmaf(wg, r2.x, accr);
            accg = fmaf(wg, r2.y, accg);
            accb = fmaf(wg, r2.z, accb);
            T = fmaf(-al, T, T);
        }
    }
    part[w][lane] = make_float4(accr, accg, accb, T);
    __syncthreads();

    if (tid < 64) {
        float R = 0.f, G = 0.f, B = 0.f, Tr = 1.f;
        #pragma unroll
        for (int s = 0; s < NSEG; ++s) {
            float4 q = part[s][tid];
            R  = fmaf(Tr, q.x, R);
            G  = fmaf(Tr, q.y, G);
            B  = fmaf(Tr, q.z, B);
            Tr *= q.w;
        }
        int x = tx + (tid & 7);
        int y = ty + (tid >> 3);
        int p = y * 128 + x;
        out[3*(size_t)p+0] = R;
        out[3*(size_t)p+1] = G;
        out[3*(size_t)p+2] = B;
    }
}

extern "C" void kernel_launch(void* const* d_in, const int* in_sizes, int n_in,
                              void* d_out, int out_size, void* d_ws, size_t ws_size,
                              hipStream_t stream) {
    const float* means     = (const float*)d_in[0];
    const float* quats     = (const float*)d_in[1];
    const float* scales    = (const float*)d_in[2];
    const float* opacities = (const float*)d_in[3];
    const float* sh        = (const float*)d_in[4];
    const float* vm        = (const float*)d_in[5];
    const float* K         = (const float*)d_in[6];

    int N = in_sizes[0] / 3;   // gaussians
    // P = out_size / 3 = 16384 pixels = 128x128 (fixed by problem setup)

    float* sorted = (float*)d_ws;   // N*12 floats

    prep_rank_kernel<<<(N + 3) / 4, 256, 0, stream>>>(
        means, quats, scales, opacities, sh, vm, K, sorted, N);
    render_tile_kernel<<<256, 1024, 0, stream>>>(
        (const float4*)sorted, (float*)d_out, N);
}

// Round 7
// 106.767 us; speedup vs baseline: 1.1353x; 1.1353x over previous
//
#include <hip/hip_runtime.h>
#include <math.h>

#define SH_C0     0.28209479177387814f
#define EPS2D     0.3f
#define NEARZ     0.01f
#define ALPHA_MIN (1.0f/255.0f)
#define ALPHA_MAX 0.999f
#define LOG2E     1.4426950408889634f

#define NSEG   16     // waves per render block (= depth segments of the tile list)
#define MAXN   2048   // problem size (list/LDS sizing)

// ---------------------------------------------------------------------------
// Fused preprocess + stable-rank + scatter. One 64-lane wave per gaussian.
// Record (12 floats, 48B, float4-aligned), indexed by depth rank:
//   r0 = {u, v, rx, ry}   rx,ry = conservative alpha>=1/255 ellipse bbox
//                         half-extents (+0.5px pad) -> culling is exact
//   r1 = {0.5*conA*L2E, conB*L2E, 0.5*conC*L2E, op}
//   r2 = {cr, cg, cb, 0}
// Invalid (z<=NEAR, det<=0) or op<1/255: u=v=-1e9, rx=ry=0 -> culled from
// every tile == reference's alpha=0 for those gaussians.
// Rank key = (zc > NEAR ? zc : +inf), stable tie-break j<i: permutation
// matches jnp.argsort order exactly for all contributing gaussians.
// ---------------------------------------------------------------------------
__global__ __launch_bounds__(256) void prep_rank_kernel(
        const float* __restrict__ means,
        const float* __restrict__ quats,
        const float* __restrict__ scales,
        const float* __restrict__ opacities,
        const float* __restrict__ sh,
        const float* __restrict__ vm,
        const float* __restrict__ K,
        float* __restrict__ sorted,
        int N) {
    int wave = blockIdx.x * 4 + (threadIdx.x >> 6);
    int lane = threadIdx.x & 63;
    if (wave >= N) return;
    int i = wave;

    float r00=vm[0], r01=vm[1], r02=vm[2],  t0=vm[3];
    float r10=vm[4], r11=vm[5], r12=vm[6],  t1=vm[7];
    float r20=vm[8], r21=vm[9], r22=vm[10], t2=vm[11];

    // --- stable rank: count keys strictly smaller (ties: j < i) ---
    float mx = means[3*i+0], my = means[3*i+1], mz = means[3*i+2];
    float zci = r20*mx + r21*my + r22*mz + t2;
    float keyi = (zci > NEARZ) ? zci : INFINITY;
    int cnt = 0;
    for (int j = lane; j < N; j += 64) {
        float ax = means[3*j+0], ay = means[3*j+1], az = means[3*j+2];
        float zcj = r20*ax + r21*ay + r22*az + t2;
        float keyj = (zcj > NEARZ) ? zcj : INFINITY;
        cnt += (keyj < keyi) || (keyj == keyi && j < i);
    }
    #pragma unroll
    for (int off = 32; off > 0; off >>= 1)
        cnt += __shfl_xor(cnt, off, 64);

    // --- preprocess (redundant across lanes; uniform loads) ---
    float qw = quats[4*i+0], qx = quats[4*i+1], qy = quats[4*i+2], qz = quats[4*i+3];
    float rqn = rsqrtf(qw*qw + qx*qx + qy*qy + qz*qz);
    qw *= rqn; qx *= rqn; qy *= rqn; qz *= rqn;

    float R00 = 1.f - 2.f*(qy*qy + qz*qz);
    float R01 = 2.f*(qx*qy - qw*qz);
    float R02 = 2.f*(qx*qz + qw*qy);
    float R10 = 2.f*(qx*qy + qw*qz);
    float R11 = 1.f - 2.f*(qx*qx + qz*qz);
    float R12 = 2.f*(qy*qz - qw*qx);
    float R20 = 2.f*(qx*qz - qw*qy);
    float R21 = 2.f*(qy*qz + qw*qx);
    float R22 = 1.f - 2.f*(qx*qx + qy*qy);

    float s0 = fminf(expf(scales[3*i+0]), 10.f);
    float s1 = fminf(expf(scales[3*i+1]), 10.f);
    float s2 = fminf(expf(scales[3*i+2]), 10.f);

    float M00=R00*s0, M01=R01*s1, M02=R02*s2;
    float M10=R10*s0, M11=R11*s1, M12=R12*s2;
    float M20=R20*s0, M21=R21*s1, M22=R22*s2;

    float c00 = M00*M00 + M01*M01 + M02*M02;
    float c01 = M00*M10 + M01*M11 + M02*M12;
    float c02 = M00*M20 + M01*M21 + M02*M22;
    float c11 = M10*M10 + M11*M11 + M12*M12;
    float c12 = M10*M20 + M11*M21 + M12*M22;
    float c22 = M20*M20 + M21*M21 + M22*M22;

    float xc = r00*mx + r01*my + r02*mz + t0;
    float yc = r10*mx + r11*my + r12*mz + t1;
    float zc = zci;

    float T00 = r00*c00 + r01*c01 + r02*c02;
    float T01 = r00*c01 + r01*c11 + r02*c12;
    float T02 = r00*c02 + r01*c12 + r02*c22;
    float T10 = r10*c00 + r11*c01 + r12*c02;
    float T11 = r10*c01 + r11*c11 + r12*c12;
    float T12 = r10*c02 + r11*c12 + r12*c22;
    float T20 = r20*c00 + r21*c01 + r22*c02;
    float T21 = r20*c01 + r21*c11 + r22*c12;
    float T22 = r20*c02 + r21*c12 + r22*c22;
    float V00 = T00*r00 + T01*r01 + T02*r02;
    float V01 = T00*r10 + T01*r11 + T02*r12;
    float V02 = T00*r20 + T01*r21 + T02*r22;
    float V11 = T10*r10 + T11*r11 + T12*r12;
    float V12 = T10*r20 + T11*r21 + T12*r22;
    float V22 = T20*r20 + T21*r21 + T22*r22;

    float fx = K[0], cx = K[2], fy = K[4], cy = K[5];

    bool valid = zc > NEARZ;
    float zs = valid ? zc : 1.0f;
    float rz = 1.0f / zs;
    float u = fx*xc*rz + cx;
    float v = fy*yc*rz + cy;
    float J00 = fx*rz;
    float J02 = -fx*xc*rz*rz;
    float J11 = fy*rz;
    float J12 = -fy*yc*rz*rz;

    float a = J00*J00*V00 + 2.f*J00*J02*V02 + J02*J02*V22 + EPS2D;
    float b = J00*(J11*V01 + J12*V02) + J02*(J11*V12 + J12*V22);
    float c = J11*J11*V11 + 2.f*J11*J12*V12 + J12*J12*V22 + EPS2D;
    float det = a*c - b*b;
    valid = valid && (det > 0.f);
    float det_s = valid ? det : 1.0f;
    float conA =  c / det_s;
    float conB = -b / det_s;
    float conC =  a / det_s;

    float op  = 1.0f / (1.0f + expf(-opacities[i]));
    float cr = fmaxf(sh[3*i+0]*SH_C0 + 0.5f, 0.f);
    float cg = fmaxf(sh[3*i+1]*SH_C0 + 0.5f, 0.f);
    float cb = fmaxf(sh[3*i+2]*SH_C0 + 0.5f, 0.f);

    // conservative alpha>=1/255 ellipse half-extents
    float smax = logf(op * 255.0f);
    bool vis = valid && (smax > 0.f);
    float denom = conA*conC - conB*conB;
    float rxe = 0.f, rye = 0.f;
    float uu = -1.0e9f, vv = -1.0e9f;
    float e4 = 0.f, e5 = 0.f, e6 = 0.f, e7 = 0.f;
    if (vis) {
        float inv = 2.f * smax / denom;
        rxe = sqrtf(fmaxf(inv * conC, 0.f)) + 0.5f;
        rye = sqrtf(fmaxf(inv * conA, 0.f)) + 0.5f;
        uu = u; vv = v;
        e4 = 0.5f*conA*LOG2E; e5 = conB*LOG2E; e6 = 0.5f*conC*LOG2E; e7 = op;
    }

    if (lane < 12) {
        float val;
        switch (lane) {
            case 0:  val = uu;  break;
            case 1:  val = vv;  break;
            case 2:  val = rxe; break;
            case 3:  val = rye; break;
            case 4:  val = e4;  break;
            case 5:  val = e5;  break;
            case 6:  val = e6;  break;
            case 7:  val = e7;  break;
            case 8:  val = cr;  break;
            case 9:  val = cg;  break;
            case 10: val = cb;  break;
            default: val = 0.f; break;
        }
        sorted[12*(size_t)cnt + lane] = val;
    }
}

// ---------------------------------------------------------------------------
// Two-phase tiled render. 256 blocks (one per 8x8-px tile) x 1024 threads.
// Phase 0 (bin): 16 waves cooperatively test all N gaussians vs the tile bbox
//   (ballot per 64-gaussian word, order-preserving compaction via LDS prefix
//   of per-wave counts) -> rank-ordered u16 index list in LDS.
// Phase 1 (composite): wave w walks a contiguous chunk of the list with a
//   BRANCH-FREE dense body (uniform ds_read index -> scalar record loads ->
//   ~16 VALU); wave-uniform __all(T<1e-9) early-break (truncation < 1e-7,
//   far below tolerance). Per-wave (C,T) partials folded in depth order in
//   LDS, written directly to out. Conservative culling => output identical
//   to the brute-force version.
// ---------------------------------------------------------------------------
__global__ __launch_bounds__(1024, 4) void render_tile_kernel(
        const float4* __restrict__ rec,
        float* __restrict__ out,
        int N) {
    __shared__ unsigned long long masks[(MAXN + 63) / 64];
    __shared__ int cnts[NSEG];
    __shared__ unsigned short list[MAXN];
    __shared__ float4 part[NSEG][64];

    int tid  = threadIdx.x;
    int lane = tid & 63;
    int w    = tid >> 6;                 // wave id 0..15
    int t    = blockIdx.x;               // tile id 0..255
    int tx   = (t & 15) << 3;
    int ty   = (t >> 4) << 3;

    float tcx = (float)tx + 4.0f;        // pixel centers span [tx+0.5, tx+7.5]
    float tcy = (float)ty + 4.0f;
    float px  = (float)(tx + (lane & 7)) + 0.5f;
    float py  = (float)(ty + (lane >> 3)) + 0.5f;

    // ---- phase 0: ballot + order-preserving compaction ----
    int nwords = (N + 63) >> 6;
    int wpw    = (nwords + NSEG - 1) / NSEG;   // contiguous words per wave
    int w0     = w * wpw;
    int w1     = min(w0 + wpw, nwords);

    int mycnt = 0;
    for (int word = w0; word < w1; ++word) {
        int g = (word << 6) + lane;
        bool hit = false;
        if (g < N) {
            float4 r0 = rec[3*(size_t)g];        // u, v, rx, ry
            hit = (fabsf(r0.x - tcx) <= r0.z + 3.5f) &&
                  (fabsf(r0.y - tcy) <= r0.w + 3.5f);
        }
        unsigned long long m = __ballot(hit);
        if (lane == 0) masks[word] = m;
        mycnt += (int)__popcll(m);
    }
    if (lane == 0) cnts[w] = mycnt;
    __syncthreads();

    int off = 0, L = 0;
    #pragma unroll
    for (int s = 0; s < NSEG; ++s) {
        int cs = cnts[s];
        if (s < w) off += cs;
        L += cs;
    }
    unsigned long long lt = (1ull << lane) - 1ull;
    for (int word = w0; word < w1; ++word) {
        unsigned long long m = masks[word];
        bool hit = (m >> lane) & 1ull;
        int p = (int)__popcll(m & lt);
        if (hit) list[off + p] = (unsigned short)((word << 6) + lane);
        off += (int)__popcll(m);
    }
    __syncthreads();

    // ---- phase 1: dense composite over this wave's chunk ----
    int chunk = (L + NSEG - 1) / NSEG;
    int i0 = w * chunk;
    int i1 = min(i0 + chunk, L);

    float accr = 0.f, accg = 0.f, accb = 0.f, T = 1.f;
    for (int i = i0; i < i1; ++i) {
        int idx = (int)list[i];                          // uniform ds_read
        idx = __builtin_amdgcn_readfirstlane(idx);       // force scalar
        const float4* r = rec + 3*(size_t)idx;
        float4 r0 = r[0];                                // u, v, -, -
        float4 r1 = r[1];                                // A2', B', C2', op
        float4 r2 = r[2];                                // cr, cg, cb, -
        float dx = px - r0.x, dy = py - r0.y;
        float tt  = fmaf(r1.x, dx, r1.y * dy);
        float arg = fmaf(-r1.z, dy*dy, -dx*tt);          // -sigma*log2e
        float al  = r1.w * __builtin_amdgcn_exp2f(arg);
        al = fminf(al, ALPHA_MAX);
        al = (al >= ALPHA_MIN) ? al : 0.f;
        float wg = T * al;
        accr = fmaf(wg, r2.x, accr);
        accg = fmaf(wg, r2.y, accg);
        accb = fmaf(wg, r2.z, accb);
        T = fmaf(-al, T, T);
        if (__all(T < 1e-9f)) break;   // remaining contribution < 1e-7
    }
    part[w][lane] = make_float4(accr, accg, accb, T);
    __syncthreads();

    if (tid < 64) {
        float R = 0.f, G = 0.f, B = 0.f, Tr = 1.f;
        #pragma unroll
        for (int s = 0; s < NSEG; ++s) {
            float4 q = part[s][tid];
            R  = fmaf(Tr, q.x, R);
            G  = fmaf(Tr, q.y, G);
            B  = fmaf(Tr, q.z, B);
            Tr *= q.w;
        }
        int x = tx + (tid & 7);
        int y = ty + (tid >> 3);
        int p = y * 128 + x;
        out[3*(size_t)p+0] = R;
        out[3*(size_t)p+1] = G;
        out[3*(size_t)p+2] = B;
    }
}

extern "C" void kernel_launch(void* const* d_in, const int* in_sizes, int n_in,
                              void* d_out, int out_size, void* d_ws, size_t ws_size,
                              hipStream_t stream) {
    const float* means     = (const float*)d_in[0];
    const float* quats     = (const float*)d_in[1];
    const float* scales    = (const float*)d_in[2];
    const float* opacities = (const float*)d_in[3];
    const float* sh        = (const float*)d_in[4];
    const float* vm        = (const float*)d_in[5];
    const float* K         = (const float*)d_in[6];

    int N = in_sizes[0] / 3;   // gaussians (2048)
    // P = out_size / 3 = 16384 pixels = 128x128 (fixed by problem setup)

    float* sorted = (float*)d_ws;   // N*12 floats

    prep_rank_kernel<<<(N + 3) / 4, 256, 0, stream>>>(
        means, quats, scales, opacities, sh, vm, K, sorted, N);
    render_tile_kernel<<<256, 1024, 0, stream>>>(
        (const float4*)sorted, (float*)d_out, N);
}